// Round 3
// baseline (8888.512 us; speedup 1.0000x reference)
//
#include <hip/hip_runtime.h>

#define NP 128
#define NPE 127

// ---- main-kernel LDS weight offsets (floats) ----
#define MW_W2   0        // e_w2 32x32
#define MW_B2   1024
#define MW_CW1  1056     // c_w1 32x32
#define MW_CB1  2080
#define MW_CW2  2112
#define MW_AW   2144
#define MW_AB   2176     // 1
#define MW_R64  2180     // e_w1 row 64 (d^2 row)
#define MW_R65  2212     // e_w1 row 65 (ds^2 row)
#define MW_NW1  2244     // n_w1 64x32
#define MW_NB1  4292
#define MW_NW2  4324     // n_w2 32x32
#define MW_NB2  5348
#define MW_TOT  5380     // 21520 bytes

__device__ __forceinline__ float fast_rcp(float x) { return __builtin_amdgcn_rcpf(x); }
__device__ __forceinline__ float sigmoidf_(float x) { return fast_rcp(1.0f + __expf(-x)); }
__device__ __forceinline__ float siluf(float x) { return x * sigmoidf_(x); }
__device__ __forceinline__ float tanhf_fast(float x) {
    return 1.0f - 2.0f * fast_rcp(1.0f + __expf(2.0f * x));
}

// ---------- precompute: HC[row][0:32] = h@W1[0:32]+b1 ; HC[row][32:64] = h@W1[32:64] ----------
__global__ __launch_bounds__(128)
void hc_kernel(const float* __restrict__ Hin, const float* __restrict__ EW1,
               const float* __restrict__ EB1, float* __restrict__ HC)
{
    __shared__ float sw[64 * 32 + 32];
    const int t = threadIdx.x;
    for (int idx = t; idx < 64 * 32; idx += 128) sw[idx] = EW1[idx];
    if (t < 32) sw[2048 + t] = EB1[t];
    __syncthreads();

    const int row = blockIdx.x * 128 + t;   // 0..16383
    const float* hp = &Hin[row * 32];
    float h[32];
    #pragma unroll
    for (int g = 0; g < 8; ++g) {
        const float4 v = *(const float4*)&hp[g * 4];
        h[g*4+0] = v.x; h[g*4+1] = v.y; h[g*4+2] = v.z; h[g*4+3] = v.w;
    }
    float a1[32], a2[32];
    #pragma unroll
    for (int o = 0; o < 32; ++o) { a1[o] = sw[2048 + o]; a2[o] = 0.f; }
    #pragma unroll
    for (int k = 0; k < 32; ++k) {
        const float a = h[k];
        #pragma unroll
        for (int o = 0; o < 32; ++o) {
            a1[o] = fmaf(a, sw[k * 32 + o], a1[o]);
            a2[o] = fmaf(a, sw[(32 + k) * 32 + o], a2[o]);
        }
    }
    float* op = &HC[row * 64];
    #pragma unroll
    for (int o = 0; o < 32; ++o) { op[o] = a1[o]; op[32 + o] = a2[o]; }
}

// ---------- main: 1 wave = 1 node, 2 edge passes per lane ----------
__global__ __launch_bounds__(256)
void eq_gnn_main(const float* __restrict__ X, const float* __restrict__ Hin,
                 const float* __restrict__ DS, const float* __restrict__ HC,
                 const float* EW1, const float* EW2, const float* EB2,
                 const float* NW1, const float* NB1, const float* NW2, const float* NB2,
                 const float* CW1, const float* CB1, const float* CW2,
                 const float* AW,  const float* AB,
                 float* __restrict__ OUT)
{
    __shared__ float sw[MW_TOT];
    const int t = threadIdx.x;

    // ---- stage weights ----
    {
        const float* srcs[13] = {EW2, EB2, CW1, CB1, CW2, AW, AB, EW1 + 64*32, EW1 + 65*32,
                                 NW1, NB1, NW2, NB2};
        const int    offs[13] = {MW_W2, MW_B2, MW_CW1, MW_CB1, MW_CW2, MW_AW, MW_AB,
                                 MW_R64, MW_R65, MW_NW1, MW_NB1, MW_NW2, MW_NB2};
        const int    cnts[13] = {1024, 32, 1024, 32, 32, 32, 1, 32, 32, 2048, 32, 1024, 32};
        #pragma unroll
        for (int a = 0; a < 13; ++a)
            for (int idx = t; idx < cnts[a]; idx += 256)
                sw[offs[a] + idx] = srcs[a][idx];
    }
    __syncthreads();

    const int lane = t & 63;
    const int node = blockIdx.x * 4 + (t >> 6);   // wave -> node
    const int b = node >> 7, i = node & 127;

    const float* xip = &X[b * 384 + i * 3];
    const float xi0 = xip[0], xi1 = xip[1], xi2 = xip[2];

    float ms[32];
    #pragma unroll
    for (int o = 0; o < 32; ++o) ms[o] = 0.f;
    float xc0 = 0.f, xc1 = 0.f, xc2 = 0.f;

    #pragma unroll 1
    for (int e = 0; e < 2; ++e) {
        const int slot = lane + (e << 6);
        const float validf = (slot < NPE) ? 1.f : 0.f;
        const int js = (slot < NPE) ? slot : 0;
        const int j = js + ((js >= i) ? 1 : 0);

        const float* xjp = &X[b * 384 + j * 3];
        const float r0 = xi0 - xjp[0], r1 = xi1 - xjp[1], r2 = xi2 - xjp[2];
        const float d2 = r0*r0 + r1*r1 + r2*r2 + 1e-6f;
        const float d  = sqrtf(d2);
        const float dsv = DS[b * 16256 + i * 127 + js];
        const float ds2 = dsv * dsv;

        // ---- layer-1 via precomputed HC ----
        const float* hcip = &HC[node * 64];                 // uniform (L1 broadcast)
        const float* hcjp = &HC[(b * 128 + j) * 64 + 32];
        float t1[32];
        #pragma unroll
        for (int g = 0; g < 8; ++g) {
            const float4 hi = *(const float4*)&hcip[g * 4];
            const float4 hj = *(const float4*)&hcjp[g * 4];
            const float4 w6 = *(const float4*)&sw[MW_R64 + g * 4];
            const float4 w7 = *(const float4*)&sw[MW_R65 + g * 4];
            t1[g*4+0] = siluf(fmaf(ds2, w7.x, fmaf(d2, w6.x, hi.x + hj.x)));
            t1[g*4+1] = siluf(fmaf(ds2, w7.y, fmaf(d2, w6.y, hi.y + hj.y)));
            t1[g*4+2] = siluf(fmaf(ds2, w7.z, fmaf(d2, w6.z, hi.z + hj.z)));
            t1[g*4+3] = siluf(fmaf(ds2, w7.w, fmaf(d2, w6.w, hi.w + hj.w)));
        }

        // ---- layer 2 ----
        float acc[32];
        #pragma unroll
        for (int g = 0; g < 8; ++g) {
            const float4 bv = *(const float4*)&sw[MW_B2 + g * 4];
            acc[g*4+0] = bv.x; acc[g*4+1] = bv.y; acc[g*4+2] = bv.z; acc[g*4+3] = bv.w;
        }
        #pragma unroll
        for (int k = 0; k < 32; ++k) {
            const float a = t1[k];
            #pragma unroll
            for (int g = 0; g < 8; ++g) {
                const float4 wv = *(const float4*)&sw[MW_W2 + k * 32 + g * 4];
                acc[g*4+0] = fmaf(a, wv.x, acc[g*4+0]);
                acc[g*4+1] = fmaf(a, wv.y, acc[g*4+1]);
                acc[g*4+2] = fmaf(a, wv.z, acc[g*4+2]);
                acc[g*4+3] = fmaf(a, wv.w, acc[g*4+3]);
            }
        }
        float m[32];
        #pragma unroll
        for (int o = 0; o < 32; ++o) m[o] = siluf(acc[o]);

        // ---- attention gate (validity folded into att) ----
        float aacc = sw[MW_AB];
        #pragma unroll
        for (int g = 0; g < 8; ++g) {
            const float4 av = *(const float4*)&sw[MW_AW + g * 4];
            aacc = fmaf(m[g*4+0], av.x, aacc); aacc = fmaf(m[g*4+1], av.y, aacc);
            aacc = fmaf(m[g*4+2], av.z, aacc); aacc = fmaf(m[g*4+3], av.w, aacc);
        }
        const float att = sigmoidf_(aacc) * validf;
        #pragma unroll
        for (int o = 0; o < 32; ++o) m[o] *= att;

        // ---- coord head ----
        float cacc[32];
        #pragma unroll
        for (int g = 0; g < 8; ++g) {
            const float4 bv = *(const float4*)&sw[MW_CB1 + g * 4];
            cacc[g*4+0] = bv.x; cacc[g*4+1] = bv.y; cacc[g*4+2] = bv.z; cacc[g*4+3] = bv.w;
        }
        #pragma unroll
        for (int k = 0; k < 32; ++k) {
            const float a = m[k];
            #pragma unroll
            for (int g = 0; g < 8; ++g) {
                const float4 wv = *(const float4*)&sw[MW_CW1 + k * 32 + g * 4];
                cacc[g*4+0] = fmaf(a, wv.x, cacc[g*4+0]);
                cacc[g*4+1] = fmaf(a, wv.y, cacc[g*4+1]);
                cacc[g*4+2] = fmaf(a, wv.z, cacc[g*4+2]);
                cacc[g*4+3] = fmaf(a, wv.w, cacc[g*4+3]);
            }
        }
        float tr = 0.f;
        #pragma unroll
        for (int k = 0; k < 32; ++k) tr = fmaf(siluf(cacc[k]), sw[MW_CW2 + k], tr);
        const float coef = tanhf_fast(tr) * fast_rcp(d + 1.0f) * validf;

        // ---- accumulate per-lane partials ----
        #pragma unroll
        for (int o = 0; o < 32; ++o) ms[o] += m[o];
        xc0 = fmaf(r0, coef, xc0); xc1 = fmaf(r1, coef, xc1); xc2 = fmaf(r2, coef, xc2);
    }

    // ---- butterfly reduction across the wave (leaves full sum in every lane) ----
    #pragma unroll
    for (int o = 0; o < 32; ++o) {
        float v = ms[o];
        v += __shfl_xor(v, 1, 64);  v += __shfl_xor(v, 2, 64);
        v += __shfl_xor(v, 4, 64);  v += __shfl_xor(v, 8, 64);
        v += __shfl_xor(v, 16, 64); v += __shfl_xor(v, 32, 64);
        ms[o] = v;
    }
    {
        float v0 = xc0, v1 = xc1, v2 = xc2;
        v0 += __shfl_xor(v0, 1, 64); v1 += __shfl_xor(v1, 1, 64); v2 += __shfl_xor(v2, 1, 64);
        v0 += __shfl_xor(v0, 2, 64); v1 += __shfl_xor(v1, 2, 64); v2 += __shfl_xor(v2, 2, 64);
        v0 += __shfl_xor(v0, 4, 64); v1 += __shfl_xor(v1, 4, 64); v2 += __shfl_xor(v2, 4, 64);
        v0 += __shfl_xor(v0, 8, 64); v1 += __shfl_xor(v1, 8, 64); v2 += __shfl_xor(v2, 8, 64);
        v0 += __shfl_xor(v0, 16, 64); v1 += __shfl_xor(v1, 16, 64); v2 += __shfl_xor(v2, 16, 64);
        v0 += __shfl_xor(v0, 32, 64); v1 += __shfl_xor(v1, 32, 64); v2 += __shfl_xor(v2, 32, 64);
        xc0 = v0; xc1 = v1; xc2 = v2;
    }

    // ---- x output ----
    if (lane < 3) {
        const float xiv = (lane == 0) ? xi0 : ((lane == 1) ? xi1 : xi2);
        const float xcv = (lane == 0) ? xc0 : ((lane == 1) ? xc1 : xc2);
        OUT[b * 384 + i * 3 + lane] = xiv + xcv * 5.0f;
    }

    // ---- node MLP (in-wave; lanes 32..63 duplicate lanes 0..31) ----
    const float* hp = &Hin[node * 32];
    float h[32];
    #pragma unroll
    for (int g = 0; g < 8; ++g) {
        const float4 v = *(const float4*)&hp[g * 4];
        h[g*4+0] = v.x; h[g*4+1] = v.y; h[g*4+2] = v.z; h[g*4+3] = v.w;
    }
    const int o = lane & 31;
    float a1 = sw[MW_NB1 + o];
    #pragma unroll
    for (int k = 0; k < 32; ++k) a1 = fmaf(h[k],  sw[MW_NW1 + k * 32 + o], a1);
    #pragma unroll
    for (int k = 0; k < 32; ++k) a1 = fmaf(ms[k], sw[MW_NW1 + (32 + k) * 32 + o], a1);
    const float s1 = siluf(a1);
    float a2 = sw[MW_NB2 + o];
    #pragma unroll
    for (int k = 0; k < 32; ++k) a2 = fmaf(__shfl(s1, k, 64), sw[MW_NW2 + k * 32 + o], a2);
    if (lane < 32)
        OUT[49152 + node * 32 + o] = Hin[node * 32 + o] + a2;
}

extern "C" void kernel_launch(void* const* d_in, const int* in_sizes, int n_in,
                              void* d_out, int out_size, void* d_ws, size_t ws_size,
                              hipStream_t stream) {
    (void)in_sizes; (void)n_in; (void)out_size; (void)ws_size;
    float* HC = (float*)d_ws;   // 16384 x 64 floats = 4 MB

    hc_kernel<<<dim3(128), dim3(128), 0, stream>>>(
        (const float*)d_in[1], (const float*)d_in[3], (const float*)d_in[4], HC);

    eq_gnn_main<<<dim3(4096), dim3(256), 0, stream>>>(
        (const float*)d_in[0],  (const float*)d_in[1],  (const float*)d_in[2], HC,
        (const float*)d_in[3],  (const float*)d_in[5],  (const float*)d_in[6],
        (const float*)d_in[7],  (const float*)d_in[8],  (const float*)d_in[9],  (const float*)d_in[10],
        (const float*)d_in[11], (const float*)d_in[12], (const float*)d_in[13],
        (const float*)d_in[14], (const float*)d_in[15],
        (float*)d_out);
}

// Round 4
// 197.577 us; speedup vs baseline: 44.9875x; 44.9875x over previous
//
#include <hip/hip_runtime.h>
#include <hip/hip_bf16.h>

#define NP 128
#define NPE 127

typedef short v8s __attribute__((ext_vector_type(8)));
typedef float v4f __attribute__((ext_vector_type(4)));

// LDS float offsets
#define L_NW1 0
#define L_NB1 2048
#define L_NW2 2080
#define L_NB2 3104
#define L_BUF 3136              // 4 waves x 576 floats ([16 edges][36])
#define L_TOT (3136 + 4 * 576)  // 5440 floats = 21.8 KB

__device__ __forceinline__ float fast_rcp(float x) { return __builtin_amdgcn_rcpf(x); }
__device__ __forceinline__ float sigmoidf_(float x) { return fast_rcp(1.0f + __expf(-x)); }
__device__ __forceinline__ float siluf(float x) { return x * sigmoidf_(x); }
__device__ __forceinline__ float tanhf_fast(float x) {
    return 1.0f - 2.0f * fast_rcp(1.0f + __expf(2.0f * x));
}
__device__ __forceinline__ short f2bf(float x) {
    __hip_bfloat16 h = __float2bfloat16(x);
    return *reinterpret_cast<short*>(&h);
}

// ---------- precompute: HC[row][0:32] = h@W1[rows 0:32]+b1 ; HC[row][32:64] = h@W1[rows 32:64] ----------
__global__ __launch_bounds__(128)
void hc_kernel(const float* __restrict__ Hin, const float* __restrict__ EW1,
               const float* __restrict__ EB1, float* __restrict__ HC)
{
    __shared__ float sw[64 * 32 + 32];
    const int t = threadIdx.x;
    for (int idx = t; idx < 64 * 32; idx += 128) sw[idx] = EW1[idx];
    if (t < 32) sw[2048 + t] = EB1[t];
    __syncthreads();

    const int row = blockIdx.x * 128 + t;
    const float* hp = &Hin[row * 32];
    float h[32];
    #pragma unroll
    for (int g = 0; g < 8; ++g) {
        const float4 v = *(const float4*)&hp[g * 4];
        h[g*4+0] = v.x; h[g*4+1] = v.y; h[g*4+2] = v.z; h[g*4+3] = v.w;
    }
    float a1[32], a2[32];
    #pragma unroll
    for (int o = 0; o < 32; ++o) { a1[o] = sw[2048 + o]; a2[o] = 0.f; }
    #pragma unroll
    for (int k = 0; k < 32; ++k) {
        const float a = h[k];
        #pragma unroll
        for (int o = 0; o < 32; ++o) {
            a1[o] = fmaf(a, sw[k * 32 + o], a1[o]);
            a2[o] = fmaf(a, sw[(32 + k) * 32 + o], a2[o]);
        }
    }
    float* op = &HC[row * 64];
    #pragma unroll
    for (int o = 0; o < 32; ++o) { op[o] = a1[o]; op[32 + o] = a2[o]; }
}

// ---------- main: 1 wave = 1 node; 8 tiles x 16 edges; MFMA for the two 32x32 layers ----------
__global__ __launch_bounds__(256)
void eq_gnn_main(const float* __restrict__ X, const float* __restrict__ Hin,
                 const float* __restrict__ DS, const float* __restrict__ HC,
                 const float* __restrict__ EW1, const float* __restrict__ EW2,
                 const float* __restrict__ EB2,
                 const float* __restrict__ NW1, const float* __restrict__ NB1,
                 const float* __restrict__ NW2, const float* __restrict__ NB2,
                 const float* __restrict__ CW1, const float* __restrict__ CB1,
                 const float* __restrict__ CW2,
                 const float* __restrict__ AW,  const float* __restrict__ AB,
                 float* __restrict__ OUT)
{
    __shared__ float sw[L_TOT];
    const int tid = threadIdx.x;

    // stage node-MLP weights (only LDS-resident weights)
    for (int idx = tid; idx < 2048; idx += 256) sw[L_NW1 + idx] = NW1[idx];
    for (int idx = tid; idx < 1024; idx += 256) sw[L_NW2 + idx] = NW2[idx];
    if (tid < 32) { sw[L_NB1 + tid] = NB1[tid]; sw[L_NB2 + tid] = NB2[tid]; }
    __syncthreads();

    const int lane = tid & 63;
    const int wid  = tid >> 6;
    const int node = blockIdx.x * 4 + wid;
    const int b = node >> 7, i = node & 127;
    const int m16 = lane & 15;   // A-frag row (edge-in-tile) / C-frag col
    const int q   = lane >> 4;   // quad: A/B k-chunk, C row-group

    float* buf = &sw[L_BUF + wid * 576];

    // ---- per-lane weight fragments (registers, loaded once from global) ----
    // B-frag for 16x16x32: B[k][n], n = lane&15 (+16*t for n-half t), k = q*8+j
    v8s Bw2[2], Bc1[2];
    #pragma unroll
    for (int t = 0; t < 2; ++t)
        #pragma unroll
        for (int j = 0; j < 8; ++j) {
            Bw2[t][j] = f2bf(EW2[(q * 8 + j) * 32 + m16 + 16 * t]);
            Bc1[t][j] = f2bf(CW1[(q * 8 + j) * 32 + m16 + 16 * t]);
        }
    float w64c[8], w65c[8], awc[8], cw2c[8], hcic[8];
    #pragma unroll
    for (int j = 0; j < 8; ++j) {
        w64c[j] = EW1[64 * 32 + q * 8 + j];
        w65c[j] = EW1[65 * 32 + q * 8 + j];
        awc[j]  = AW[q * 8 + j];
        cw2c[j] = CW2[q * 8 + j];
        hcic[j] = HC[node * 64 + q * 8 + j];   // h_i@W1 + b1, chunk q
    }
    const float b2a  = EB2[m16], b2b  = EB2[m16 + 16];
    const float cb1a = CB1[m16], cb1b = CB1[m16 + 16];
    const float ab0  = AB[0];
    const float xi0 = X[b * 384 + i * 3 + 0];
    const float xi1 = X[b * 384 + i * 3 + 1];
    const float xi2 = X[b * 384 + i * 3 + 2];

    float ms[8];
    #pragma unroll
    for (int j = 0; j < 8; ++j) ms[j] = 0.f;
    float xc0 = 0.f, xc1 = 0.f, xc2 = 0.f;

    #pragma unroll 1
    for (int tl = 0; tl < 8; ++tl) {
        const int e = tl * 16 + m16;
        const float valid = (e < NPE) ? 1.f : 0.f;
        const int js = (e < NPE) ? e : 126;
        const int j = js + ((js >= i) ? 1 : 0);

        // geometry for edge m16 (same in all 4 quads)
        const float* xj = &X[b * 384 + j * 3];
        const float r0 = xi0 - xj[0], r1 = xi1 - xj[1], r2 = xi2 - xj[2];
        const float d2 = fmaf(r0, r0, fmaf(r1, r1, fmaf(r2, r2, 1e-6f)));
        const float d  = sqrtf(d2);
        const float dsv = DS[b * 16256 + i * 127 + js];
        const float ds2 = dsv * dsv;

        // ---- t1 directly in A-frag layout: lane holds edge m16, k = q*8+j ----
        const float* hcj = &HC[(b * 128 + j) * 64 + 32 + q * 8];
        const float4 hj0 = *(const float4*)&hcj[0];
        const float4 hj1 = *(const float4*)&hcj[4];
        float hjv[8] = {hj0.x, hj0.y, hj0.z, hj0.w, hj1.x, hj1.y, hj1.z, hj1.w};
        v8s A;
        #pragma unroll
        for (int jj = 0; jj < 8; ++jj) {
            float v = hcic[jj] + hjv[jj];
            v = fmaf(d2, w64c[jj], v);
            v = fmaf(ds2, w65c[jj], v);
            A[jj] = f2bf(siluf(v));
        }

        // ---- layer 2 MFMA: D[edge][n] ----
        v4f c0 = {b2a, b2a, b2a, b2a};
        v4f c1 = {b2b, b2b, b2b, b2b};
        c0 = __builtin_amdgcn_mfma_f32_16x16x32_bf16(A, Bw2[0], c0, 0, 0, 0);
        c1 = __builtin_amdgcn_mfma_f32_16x16x32_bf16(A, Bw2[1], c1, 0, 0, 0);

        // C layout: row(edge) = q*4+r, col(n) = m16 (+16 for c1). Round-trip to A layout.
        #pragma unroll
        for (int r = 0; r < 4; ++r) {
            buf[(q * 4 + r) * 36 + m16]      = siluf(c0[r]);
            buf[(q * 4 + r) * 36 + m16 + 16] = siluf(c1[r]);
        }
        const float4 mlo = *(const float4*)&buf[m16 * 36 + q * 8];
        const float4 mhi = *(const float4*)&buf[m16 * 36 + q * 8 + 4];
        float mA[8] = {mlo.x, mlo.y, mlo.z, mlo.w, mhi.x, mhi.y, mhi.z, mhi.w};

        // ---- attention gate in A layout ----
        float lg = 0.f;
        #pragma unroll
        for (int jj = 0; jj < 8; ++jj) lg = fmaf(mA[jj], awc[jj], lg);
        lg += __shfl_xor(lg, 16, 64);
        lg += __shfl_xor(lg, 32, 64);
        const float att = sigmoidf_(lg + ab0) * valid;
        v8s Ag;
        #pragma unroll
        for (int jj = 0; jj < 8; ++jj) {
            const float g = mA[jj] * att;
            ms[jj] += g;               // (edge,chunk) lives in exactly one lane
            Ag[jj] = f2bf(g);
        }

        // ---- coord head MFMA ----
        v4f e0 = {cb1a, cb1a, cb1a, cb1a};
        v4f e1 = {cb1b, cb1b, cb1b, cb1b};
        e0 = __builtin_amdgcn_mfma_f32_16x16x32_bf16(Ag, Bc1[0], e0, 0, 0, 0);
        e1 = __builtin_amdgcn_mfma_f32_16x16x32_bf16(Ag, Bc1[1], e1, 0, 0, 0);
        #pragma unroll
        for (int r = 0; r < 4; ++r) {
            buf[(q * 4 + r) * 36 + m16]      = siluf(e0[r]);
            buf[(q * 4 + r) * 36 + m16 + 16] = siluf(e1[r]);
        }
        const float4 clo = *(const float4*)&buf[m16 * 36 + q * 8];
        const float4 chi = *(const float4*)&buf[m16 * 36 + q * 8 + 4];
        float tr = clo.x * cw2c[0] + clo.y * cw2c[1] + clo.z * cw2c[2] + clo.w * cw2c[3]
                 + chi.x * cw2c[4] + chi.y * cw2c[5] + chi.z * cw2c[6] + chi.w * cw2c[7];
        tr += __shfl_xor(tr, 16, 64);
        tr += __shfl_xor(tr, 32, 64);
        const float coef = tanhf_fast(tr) * fast_rcp(d + 1.0f) * valid;

        // per-edge coord contribution (duplicated in 4 quads -> scale by 1/4 later)
        xc0 = fmaf(r0, coef, xc0);
        xc1 = fmaf(r1, coef, xc1);
        xc2 = fmaf(r2, coef, xc2);
    }

    // ---- reduce ms over the 16 edge-lanes in each quad ----
    #pragma unroll
    for (int jj = 0; jj < 8; ++jj) {
        float v = ms[jj];
        v += __shfl_xor(v, 1, 64); v += __shfl_xor(v, 2, 64);
        v += __shfl_xor(v, 4, 64); v += __shfl_xor(v, 8, 64);
        ms[jj] = v;   // quad q holds ms[q*8 .. q*8+8)
    }
    // ---- reduce xc over all 64 lanes (each edge appears 4x) ----
    {
        float v0 = xc0, v1 = xc1, v2 = xc2;
        #pragma unroll
        for (int s = 1; s < 64; s <<= 1) {
            v0 += __shfl_xor(v0, s, 64);
            v1 += __shfl_xor(v1, s, 64);
            v2 += __shfl_xor(v2, s, 64);
        }
        xc0 = v0 * 0.25f; xc1 = v1 * 0.25f; xc2 = v2 * 0.25f;
    }

    if (lane < 3) {
        const float xiv = (lane == 0) ? xi0 : ((lane == 1) ? xi1 : xi2);
        const float xcv = (lane == 0) ? xc0 : ((lane == 1) ? xc1 : xc2);
        OUT[b * 384 + i * 3 + lane] = fmaf(xcv, 5.0f, xiv);
    }

    // ---- ms -> LDS (per-wave buf, free now) for the node MLP ----
    if (m16 == 0) {
        #pragma unroll
        for (int jj = 0; jj < 8; ++jj) buf[q * 8 + jj] = ms[jj];
    }
    // node MLP: lane o = lane&31 owns output o (both half-waves duplicate)
    const int o = lane & 31;
    float a1 = sw[L_NB1 + o];
    #pragma unroll
    for (int k = 0; k < 32; ++k)
        a1 = fmaf(Hin[node * 32 + k], sw[L_NW1 + k * 32 + o], a1);
    #pragma unroll
    for (int k = 0; k < 32; ++k)
        a1 = fmaf(buf[k], sw[L_NW1 + (32 + k) * 32 + o], a1);
    const float s1 = siluf(a1);
    float a2 = sw[L_NB2 + o];
    #pragma unroll
    for (int k = 0; k < 32; ++k)
        a2 = fmaf(__shfl(s1, k, 64), sw[L_NW2 + k * 32 + o], a2);
    if (lane < 32)
        OUT[49152 + node * 32 + o] = Hin[node * 32 + o] + a2;
}

extern "C" void kernel_launch(void* const* d_in, const int* in_sizes, int n_in,
                              void* d_out, int out_size, void* d_ws, size_t ws_size,
                              hipStream_t stream) {
    (void)in_sizes; (void)n_in; (void)out_size; (void)ws_size;
    float* HC = (float*)d_ws;   // 16384 x 64 floats = 4 MB

    hc_kernel<<<dim3(128), dim3(128), 0, stream>>>(
        (const float*)d_in[1], (const float*)d_in[3], (const float*)d_in[4], HC);

    eq_gnn_main<<<dim3(4096), dim3(256), 0, stream>>>(
        (const float*)d_in[0],  (const float*)d_in[1],  (const float*)d_in[2], HC,
        (const float*)d_in[3],  (const float*)d_in[5],  (const float*)d_in[6],
        (const float*)d_in[7],  (const float*)d_in[8],  (const float*)d_in[9],  (const float*)d_in[10],
        (const float*)d_in[11], (const float*)d_in[12], (const float*)d_in[13],
        (const float*)d_in[14], (const float*)d_in[15],
        (float*)d_out);
}

// Round 5
// 170.965 us; speedup vs baseline: 51.9901x; 1.1557x over previous
//
#include <hip/hip_runtime.h>
#include <hip/hip_bf16.h>

#define NP 128
#define NPE 127

typedef short v8s __attribute__((ext_vector_type(8)));
typedef float v4f __attribute__((ext_vector_type(4)));

// LDS float offsets
#define L_HCJ  0       // 128 rows x 36 (j-half of layer-1, per batch-of-block)
#define L_GEOM 4608    // 4 waves x 128 x 8  {r0,r1,r2,rinv,d2,ds2,pad,pad}
#define L_HCI  8704    // 4 nodes x 32 (i-half incl bias)
#define L_TOT  8832    // 34.5 KB

__device__ __forceinline__ float fast_rcp(float x){ return __builtin_amdgcn_rcpf(x); }
__device__ __forceinline__ float sigmoidf_(float x){ return fast_rcp(1.0f + __expf(-x)); }
__device__ __forceinline__ float siluf(float x){ return x * sigmoidf_(x); }
__device__ __forceinline__ float tanhf_fast(float x){
    return 1.0f - 2.0f * fast_rcp(1.0f + __expf(2.0f * x));
}
__device__ __forceinline__ short f2bf(float x){
    __hip_bfloat16 h = __float2bfloat16(x);
    return *reinterpret_cast<short*>(&h);
}

__global__ __launch_bounds__(256)
void eq_gnn_fused(const float* __restrict__ X, const float* __restrict__ Hin,
                  const float* __restrict__ DS,
                  const float* __restrict__ EW1, const float* __restrict__ EB1,
                  const float* __restrict__ EW2, const float* __restrict__ EB2,
                  const float* __restrict__ NW1, const float* __restrict__ NB1,
                  const float* __restrict__ NW2, const float* __restrict__ NB2,
                  const float* __restrict__ CW1, const float* __restrict__ CB1,
                  const float* __restrict__ CW2,
                  const float* __restrict__ AW,  const float* __restrict__ AB,
                  float* __restrict__ OUT)
{
    __shared__ float sm[L_TOT];
    const int tid  = threadIdx.x;
    const int lane = tid & 63;
    const int wid  = tid >> 6;
    const int m16  = lane & 15;
    const int q    = lane >> 4;
    const int bI   = blockIdx.x >> 5;    // batch
    const int grp  = blockIdx.x & 31;
    const int i    = grp * 4 + wid;      // node within batch (this wave's node)
    const int node = bI * 128 + i;

    // ---------- prologue A: HCj[row][o] = h[row]@W1[32:64] for all 128 batch rows ----------
    {
        v8s Aj0, Aj1;   // A = W1j^T : A[m=o][k] = W1[32+k][o]
        #pragma unroll
        for (int jj = 0; jj < 8; ++jj){
            Aj0[jj] = f2bf(EW1[(32 + q*8 + jj) * 32 + m16]);
            Aj1[jj] = f2bf(EW1[(32 + q*8 + jj) * 32 + 16 + m16]);
        }
        #pragma unroll
        for (int rr = 0; rr < 2; ++rr){
            const int row = (wid * 2 + rr) * 16 + m16;
            const float* hp = &Hin[(bI * 128 + row) * 32 + q * 8];
            const float4 h0 = *(const float4*)&hp[0];
            const float4 h1 = *(const float4*)&hp[4];
            v8s Bh;
            Bh[0]=f2bf(h0.x); Bh[1]=f2bf(h0.y); Bh[2]=f2bf(h0.z); Bh[3]=f2bf(h0.w);
            Bh[4]=f2bf(h1.x); Bh[5]=f2bf(h1.y); Bh[6]=f2bf(h1.z); Bh[7]=f2bf(h1.w);
            v4f d0 = {0.f,0.f,0.f,0.f}, d1 = {0.f,0.f,0.f,0.f};
            d0 = __builtin_amdgcn_mfma_f32_16x16x32_bf16(Aj0, Bh, d0, 0, 0, 0);
            d1 = __builtin_amdgcn_mfma_f32_16x16x32_bf16(Aj1, Bh, d1, 0, 0, 0);
            #pragma unroll
            for (int r = 0; r < 4; ++r){
                sm[L_HCJ + row * 36 + q*4 + r]      = d0[r];
                sm[L_HCJ + row * 36 + 16 + q*4 + r] = d1[r];
            }
        }
    }
    // ---------- prologue B: hci (i-half + bias) for the block's 4 nodes, fp32 ----------
    if (tid < 128){
        const int nl = tid >> 5, o = tid & 31;
        const float* hp = &Hin[(bI * 128 + grp * 4 + nl) * 32];
        float acc = EB1[o];
        #pragma unroll
        for (int k = 0; k < 32; ++k) acc = fmaf(hp[k], EW1[k * 32 + o], acc);
        sm[L_HCI + nl * 32 + o] = acc;
    }
    // ---------- prologue C: per-wave geometry, lane = edge ----------
    float* sg = &sm[L_GEOM + wid * 1024];
    const float xi0 = X[bI*384 + i*3 + 0];
    const float xi1 = X[bI*384 + i*3 + 1];
    const float xi2 = X[bI*384 + i*3 + 2];
    #pragma unroll
    for (int p = 0; p < 2; ++p){
        const int slot = lane + 64 * p;
        const int js = (slot < NPE) ? slot : 126;
        const int j = js + ((js >= i) ? 1 : 0);
        const float* xj = &X[bI*384 + j*3];
        const float r0 = xi0 - xj[0], r1 = xi1 - xj[1], r2 = xi2 - xj[2];
        const float d2 = fmaf(r0, r0, fmaf(r1, r1, fmaf(r2, r2, 1e-6f)));
        const float d  = sqrtf(d2);
        const float rinv = fast_rcp(d + 1.0f);
        const float dsv = DS[bI*16256 + i*127 + js];
        *(float4*)&sg[slot*8]     = make_float4(r0, r1, r2, rinv);
        *(float2*)&sg[slot*8 + 4] = make_float2(d2, dsv * dsv);
    }
    __syncthreads();

    // ---------- persistent per-lane weight fragments (weights as A-operand) ----------
    v8s Aw20, Aw21, Ac0, Ac1;
    #pragma unroll
    for (int jj = 0; jj < 8; ++jj){
        Aw20[jj] = f2bf(EW2[(q*8 + jj) * 32 + m16]);        // A[m=f][k]=W2[k][f], half0
        Aw21[jj] = f2bf(EW2[(q*8 + jj) * 32 + 16 + m16]);   // half1
        // coord A: contraction slot (q,jj) carries original m-feature tau(q,jj)
        const int tau = (jj < 4) ? (q*4 + jj) : (16 + q*4 + (jj - 4));
        Ac0[jj] = f2bf(CW1[tau * 32 + m16]);
        Ac1[jj] = f2bf(CW1[tau * 32 + 16 + m16]);
    }
    const float4 w64a = *(const float4*)&EW1[64*32 + q*8];
    const float4 w64b = *(const float4*)&EW1[64*32 + q*8 + 4];
    const float4 w65a = *(const float4*)&EW1[65*32 + q*8];
    const float4 w65b = *(const float4*)&EW1[65*32 + q*8 + 4];
    const float4 b2A = *(const float4*)&EB2[q*4];
    const float4 b2B = *(const float4*)&EB2[16 + q*4];
    const float4 cbA = *(const float4*)&CB1[q*4];
    const float4 cbB = *(const float4*)&CB1[16 + q*4];
    const float4 cwA = *(const float4*)&CW2[q*4];
    const float4 cwB = *(const float4*)&CW2[16 + q*4];
    const float4 awA = *(const float4*)&AW[q*4];
    const float4 awB = *(const float4*)&AW[16 + q*4];
    const float ab0 = AB[0];
    const float4 hci0 = *(const float4*)&sm[L_HCI + wid*32 + q*8];
    const float4 hci1 = *(const float4*)&sm[L_HCI + wid*32 + q*8 + 4];

    float ms[8];
    #pragma unroll
    for (int jj = 0; jj < 8; ++jj) ms[jj] = 0.f;
    float xc0 = 0.f, xc1 = 0.f, xc2 = 0.f;

    // ---------- edge loop: 8 tiles x 16 edges ----------
    #pragma unroll 1
    for (int tl = 0; tl < 8; ++tl){
        const int e = tl * 16 + m16;
        const float valid = (e < NPE) ? 1.f : 0.f;
        const int js = (e < NPE) ? e : 126;
        const int j = js + ((js >= i) ? 1 : 0);

        const float2 dd = *(const float2*)&sg[e*8 + 4];             // d2, ds2
        const float4 hj0 = *(const float4*)&sm[L_HCJ + j*36 + q*8];
        const float4 hj1 = *(const float4*)&sm[L_HCJ + j*36 + q*8 + 4];

        // t1 as B-frag: slot (q,jj) = silu(hci+hcj+d2*w64+ds2*w65)[q*8+jj]
        v8s Bt;
        Bt[0] = f2bf(siluf(fmaf(dd.x, w64a.x, fmaf(dd.y, w65a.x, hci0.x + hj0.x))));
        Bt[1] = f2bf(siluf(fmaf(dd.x, w64a.y, fmaf(dd.y, w65a.y, hci0.y + hj0.y))));
        Bt[2] = f2bf(siluf(fmaf(dd.x, w64a.z, fmaf(dd.y, w65a.z, hci0.z + hj0.z))));
        Bt[3] = f2bf(siluf(fmaf(dd.x, w64a.w, fmaf(dd.y, w65a.w, hci0.w + hj0.w))));
        Bt[4] = f2bf(siluf(fmaf(dd.x, w64b.x, fmaf(dd.y, w65b.x, hci1.x + hj1.x))));
        Bt[5] = f2bf(siluf(fmaf(dd.x, w64b.y, fmaf(dd.y, w65b.y, hci1.y + hj1.y))));
        Bt[6] = f2bf(siluf(fmaf(dd.x, w64b.z, fmaf(dd.y, w65b.z, hci1.z + hj1.z))));
        Bt[7] = f2bf(siluf(fmaf(dd.x, w64b.w, fmaf(dd.y, w65b.w, hci1.w + hj1.w))));

        // layer 2: D[f][e] — lane holds edge e = m16, features q*4+r / 16+q*4+r
        v4f c0 = {b2A.x, b2A.y, b2A.z, b2A.w};
        v4f c1 = {b2B.x, b2B.y, b2B.z, b2B.w};
        c0 = __builtin_amdgcn_mfma_f32_16x16x32_bf16(Aw20, Bt, c0, 0, 0, 0);
        c1 = __builtin_amdgcn_mfma_f32_16x16x32_bf16(Aw21, Bt, c1, 0, 0, 0);
        const float s0 = siluf(c0[0]), s1 = siluf(c0[1]), s2 = siluf(c0[2]), s3 = siluf(c0[3]);
        const float s4 = siluf(c1[0]), s5 = siluf(c1[1]), s6 = siluf(c1[2]), s7 = siluf(c1[3]);

        // attention gate (partial over this lane's 8 features, then quad-sum)
        float lg = s0*awA.x + s1*awA.y + s2*awA.z + s3*awA.w
                 + s4*awB.x + s5*awB.y + s6*awB.z + s7*awB.w;
        lg += __shfl_xor(lg, 16, 64);
        lg += __shfl_xor(lg, 32, 64);
        const float att = sigmoidf_(lg + ab0) * valid;

        v8s Bm;
        float g;
        g = s0*att; ms[0] += g; Bm[0] = f2bf(g);
        g = s1*att; ms[1] += g; Bm[1] = f2bf(g);
        g = s2*att; ms[2] += g; Bm[2] = f2bf(g);
        g = s3*att; ms[3] += g; Bm[3] = f2bf(g);
        g = s4*att; ms[4] += g; Bm[4] = f2bf(g);
        g = s5*att; ms[5] += g; Bm[5] = f2bf(g);
        g = s6*att; ms[6] += g; Bm[6] = f2bf(g);
        g = s7*att; ms[7] += g; Bm[7] = f2bf(g);

        // coord head: D2[o2][e]
        v4f e0 = {cbA.x, cbA.y, cbA.z, cbA.w};
        v4f e1 = {cbB.x, cbB.y, cbB.z, cbB.w};
        e0 = __builtin_amdgcn_mfma_f32_16x16x32_bf16(Ac0, Bm, e0, 0, 0, 0);
        e1 = __builtin_amdgcn_mfma_f32_16x16x32_bf16(Ac1, Bm, e1, 0, 0, 0);
        float tr = siluf(e0[0])*cwA.x + siluf(e0[1])*cwA.y + siluf(e0[2])*cwA.z + siluf(e0[3])*cwA.w
                 + siluf(e1[0])*cwB.x + siluf(e1[1])*cwB.y + siluf(e1[2])*cwB.z + siluf(e1[3])*cwB.w;
        tr += __shfl_xor(tr, 16, 64);
        tr += __shfl_xor(tr, 32, 64);

        const float4 rv = *(const float4*)&sg[e*8];   // r0,r1,r2,rinv
        const float coef = tanhf_fast(tr) * rv.w * valid;
        xc0 = fmaf(rv.x, coef, xc0);
        xc1 = fmaf(rv.y, coef, xc1);
        xc2 = fmaf(rv.z, coef, xc2);
    }

    // ---------- reduce ms over the 16 edge-lanes within each quad ----------
    #pragma unroll
    for (int jj = 0; jj < 8; ++jj){
        float v = ms[jj];
        v += __shfl_xor(v, 1, 64); v += __shfl_xor(v, 2, 64);
        v += __shfl_xor(v, 4, 64); v += __shfl_xor(v, 8, 64);
        ms[jj] = v;
    }
    // ---------- reduce xc over all 64 lanes (each edge counted 4x) ----------
    {
        float v0 = xc0, v1 = xc1, v2 = xc2;
        #pragma unroll
        for (int s = 1; s < 64; s <<= 1){
            v0 += __shfl_xor(v0, s, 64);
            v1 += __shfl_xor(v1, s, 64);
            v2 += __shfl_xor(v2, s, 64);
        }
        xc0 = v0 * 0.25f; xc1 = v1 * 0.25f; xc2 = v2 * 0.25f;
    }

    if (lane < 3){
        const float xiv = (lane == 0) ? xi0 : ((lane == 1) ? xi1 : xi2);
        const float xcv = (lane == 0) ? xc0 : ((lane == 1) ? xc1 : xc2);
        OUT[bI*384 + i*3 + lane] = fmaf(xcv, 5.0f, xiv);
    }

    // ---------- stash ms (feature-ordered) into free per-wave LDS ----------
    if (m16 == 0){
        #pragma unroll
        for (int jj = 0; jj < 8; ++jj){
            const int tau = (jj < 4) ? (q*4 + jj) : (16 + q*4 + (jj - 4));
            sg[tau] = ms[jj];
        }
    }

    // ---------- node MLP (weights straight from global; L1-hot) ----------
    const int o = lane & 31;
    const float* hp = &Hin[node * 32];
    float a1 = NB1[o];
    #pragma unroll
    for (int k = 0; k < 32; ++k) a1 = fmaf(hp[k], NW1[k * 32 + o], a1);
    #pragma unroll
    for (int k = 0; k < 32; ++k) a1 = fmaf(sg[k], NW1[(32 + k) * 32 + o], a1);
    const float s1v = siluf(a1);
    float a2 = NB2[o];
    #pragma unroll
    for (int k = 0; k < 32; ++k) a2 = fmaf(__shfl(s1v, k, 64), NW2[k * 32 + o], a2);
    if (lane < 32)
        OUT[49152 + node * 32 + o] = hp[o] + a2;
}

extern "C" void kernel_launch(void* const* d_in, const int* in_sizes, int n_in,
                              void* d_out, int out_size, void* d_ws, size_t ws_size,
                              hipStream_t stream) {
    (void)in_sizes; (void)n_in; (void)out_size; (void)d_ws; (void)ws_size;
    eq_gnn_fused<<<dim3(4096), dim3(256), 0, stream>>>(
        (const float*)d_in[0],  (const float*)d_in[1],  (const float*)d_in[2],
        (const float*)d_in[3],  (const float*)d_in[4],  (const float*)d_in[5],  (const float*)d_in[6],
        (const float*)d_in[7],  (const float*)d_in[8],  (const float*)d_in[9],  (const float*)d_in[10],
        (const float*)d_in[11], (const float*)d_in[12], (const float*)d_in[13],
        (const float*)d_in[14], (const float*)d_in[15],
        (float*)d_out);
}